// Round 7
// baseline (453.155 us; speedup 1.0000x reference)
//
#include <hip/hip_runtime.h>

// Problem constants
#define Bn 8
#define Tn 2048
#define Dn 1024
#define Hn 1024
#define Mn (Bn * Tn)  // 16384 flattened rows of x

typedef __attribute__((ext_vector_type(8))) short bf16x8;    // 8 bf16 = 4 VGPRs (MFMA A/B frag)
typedef __attribute__((ext_vector_type(4))) short short4v;   // 4 bf16 = 8B store
typedef __attribute__((ext_vector_type(4))) float f32x4;     // 16x16 MFMA C/D frag

__device__ __forceinline__ unsigned short f2bf(float f) {
  union { float f; unsigned int u; } v; v.f = f;
  unsigned int u = v.u;
  u += 0x7FFFu + ((u >> 16) & 1u);   // RNE
  return (unsigned short)(u >> 16);
}
__device__ __forceinline__ float bf2f(unsigned short h) {
  union { unsigned int u; float f; } v; v.u = ((unsigned int)h) << 16;
  return v.f;
}

// async global->LDS, 16B per lane; lds base wave-uniform (lane writes base + lane*16B)
__device__ __forceinline__ void gload_lds16(const unsigned short* g, unsigned short* l) {
  __builtin_amdgcn_global_load_lds((const __attribute__((address_space(1))) void*)g,
                                   (__attribute__((address_space(3))) void*)l, 16, 0, 0);
}

// Chunk swizzle s(r) = (r&3) ^ ((r>>2)&3): LDS slot (row, q) holds global 16B chunk q ^ s(r).

// Single-wave staging of a 128x32-short piece (8 gloads/lane).
__device__ __forceinline__ void stg128(const unsigned short* g, size_t stride,
                                       unsigned short* lds, int lane) {
#pragma unroll
  for (int c = 0; c < 8; ++c) {
    int rl = c * 16 + (lane >> 2);
    int pos = (lane & 3) ^ (rl & 3) ^ ((rl >> 2) & 3);
    gload_lds16(g + (size_t)rl * stride + pos * 8, lds + c * 16 * 32);
  }
}

// 16x16x32 fragment reads: 8 m-frags (128 rows) at swizzled chunk csw.
__device__ __forceinline__ void rd8(const unsigned short* p, int rl15, int csw, bf16x8 fr[8]) {
#pragma unroll
  for (int m = 0; m < 8; ++m)
    fr[m] = *(const bf16x8*)&p[(m * 16 + rl15) * 32 + csw * 8];
}

#define W_VM16 asm volatile("s_waitcnt vmcnt(16)" ::: "memory")
#define W_VM0  asm volatile("s_waitcnt vmcnt(0)" ::: "memory")
#define W_LGKM0 asm volatile("s_waitcnt lgkmcnt(0)" ::: "memory")

// Single-wave 128x128 GEMM K-loop over nt BK=32 tiles, barrier-free, dbuf depth-1 prefetch.
// lds: [2][2][128*32] shorts (32 KiB). acc[8][8] f32x4. Ledger: each iter stages 16 loads;
// VM16 drains stage(t) (issued last iter), leaves stage(t+1) in flight. WAR on buf[(t+1)&1]
// closed by program order: its reads (iter t-1) are lgkm-drained before MFMA(t-1), which
// precedes stage(t+1); leading W_LGKM0 fences compiler motion across the back-edge.
#define KLOOP(Ag, sA, Bg, sB, nt, lds, lane, rl15, csw, acc)                              \
  {                                                                                        \
    stg128((Ag), (sA), &(lds)[0][0][0], lane);                                             \
    stg128((Bg), (sB), &(lds)[0][1][0], lane);                                             \
    _Pragma("unroll 1")                                                                    \
    for (int t = 0; t < (nt); ++t) {                                                       \
      W_LGKM0;                                                                             \
      const int ts = (t + 1 < (nt)) ? t + 1 : (nt)-1;                                      \
      stg128((Ag) + (size_t)ts * 32, (sA), &(lds)[(t + 1) & 1][0][0], lane);               \
      stg128((Bg) + (size_t)ts * 32, (sB), &(lds)[(t + 1) & 1][1][0], lane);               \
      W_VM16;                                                                              \
      bf16x8 a[8], b[8];                                                                   \
      rd8(&(lds)[t & 1][0][0], rl15, csw, a);                                              \
      rd8(&(lds)[t & 1][1][0], rl15, csw, b);                                              \
      _Pragma("unroll")                                                                    \
      for (int m = 0; m < 8; ++m)                                                          \
        _Pragma("unroll")                                                                  \
        for (int n = 0; n < 8; ++n)                                                        \
          acc[m][n] = __builtin_amdgcn_mfma_f32_16x16x32_bf16(a[m], b[n], acc[m][n], 0, 0, 0); \
    }                                                                                      \
    W_VM0;                                                                                 \
    W_LGKM0;                                                                               \
  }

// ---------------- fp32 -> bf16 convert (x) ----------------
__global__ __launch_bounds__(256) void k_convert(const float* __restrict__ in,
                                                 unsigned short* __restrict__ out, int n4) {
  int idx = blockIdx.x * 256 + threadIdx.x;
  if (idx >= n4) return;
  float4 v = ((const float4*)in)[idx];
  short4v o;
  o.x = (short)f2bf(v.x); o.y = (short)f2bf(v.y);
  o.z = (short)f2bf(v.z); o.w = (short)f2bf(v.w);
  *(short4v*)(out + (size_t)idx * 4) = o;
}

// ---------------- W fp32 [k][n] -> bf16 Wt [n][k], 3 weights in one dispatch ----------------
__global__ __launch_bounds__(256) void k_cvt_w_t(const float* __restrict__ W0,
                                                 const float* __restrict__ W1,
                                                 const float* __restrict__ W2,
                                                 unsigned short* __restrict__ Wt3) {
  const int n0 = blockIdx.x * 64, k0 = blockIdx.y * 64, w = blockIdx.z;
  const float* W = (w == 0) ? W0 : (w == 1) ? W1 : W2;
  unsigned short* Wt = Wt3 + (size_t)w * Hn * Dn;
  __shared__ unsigned short lT[64 * 65];
  const int tid = threadIdx.x;
#pragma unroll
  for (int p = 0; p < 2; ++p) {
    int o = tid + p * 256;
    int r = o >> 3, c = (o & 7) * 8;  // r = k offset, c = n offset
    const float* src = W + (size_t)(k0 + r) * Hn + n0 + c;
    float4 v0 = *(const float4*)src;
    float4 v1 = *(const float4*)(src + 4);
    unsigned short* d = &lT[r * 65 + c];
    d[0] = f2bf(v0.x); d[1] = f2bf(v0.y); d[2] = f2bf(v0.z); d[3] = f2bf(v0.w);
    d[4] = f2bf(v1.x); d[5] = f2bf(v1.y); d[6] = f2bf(v1.z); d[7] = f2bf(v1.w);
  }
  __syncthreads();
#pragma unroll
  for (int p = 0; p < 2; ++p) {
    int o = tid + p * 256;
    int r2 = o >> 3, c2 = (o & 7) * 8;  // r2 = n offset, c2 = k offset
    bf16x8 v;
#pragma unroll
    for (int s = 0; s < 8; ++s) v[s] = (short)lT[(c2 + s) * 65 + r2];
    *(bf16x8*)(Wt + (size_t)(n0 + r2) * Dn + k0 + c2) = v;
  }
}

// ---------------- Merged QKV projection: single-wave 128x128 blocks ----------------
// 3072 blocks x 64 thr; 4 independent blocks/CU (32 KiB LDS each), barrier-free pipeline.
// Per-wave tile 128x128: 48(a+b)=12288 < ab=16384 -> MFMA-bound (vs old 8-wave 128x64 =
// LDS-pipe-bound). m-group pinned to XCD c; V stored transposed per-batch [h][t].
__global__ __launch_bounds__(64, 1) void gemm_qkv(const unsigned short* __restrict__ A,
                                                  const unsigned short* __restrict__ Wt3,
                                                  unsigned short* __restrict__ Q,
                                                  unsigned short* __restrict__ Kb,
                                                  unsigned short* __restrict__ Vt) {
  const int f = blockIdx.x;
  const int c = f & 7;
  const int q = f >> 3;
  const int nn = q % 24;
  const int w = nn >> 3;                      // 0=Q 1=K 2=V
  const int n0 = (nn & 7) * 128;
  const int m0 = ((q / 24) * 8 + c) * 128;    // m-tile pinned to XCD c
  const unsigned short* Ag = A + (size_t)m0 * Dn;
  const unsigned short* Bg = Wt3 + (size_t)w * Hn * Dn + (size_t)n0 * Dn;
  __shared__ unsigned short lds[2][2][128 * 32];
  const int lane = threadIdx.x & 63;
  const int rl15 = lane & 15, l4 = lane >> 4;
  const int csw = (l4 ^ (lane & 3) ^ ((lane >> 2) & 3)) & 3;

  f32x4 acc[8][8];
#pragma unroll
  for (int m = 0; m < 8; ++m)
#pragma unroll
    for (int n = 0; n < 8; ++n) acc[m][n] = (f32x4)(0.f);

  KLOOP(Ag, Dn, Bg, Dn, Dn / 32, lds, lane, rl15, csw, acc);

  // epilogue: C/D layout col=lane&15, row=l4*4+reg
  if (w != 2) {
    unsigned short* Cp = (w == 0) ? Q : Kb;
#pragma unroll
    for (int m = 0; m < 8; ++m) {
      const int row = m0 + m * 16 + l4 * 4;
#pragma unroll
      for (int n = 0; n < 8; ++n) {
        const int col = n0 + n * 16 + rl15;
#pragma unroll
        for (int r = 0; r < 4; ++r)
          Cp[(size_t)(row + r) * Hn + col] = f2bf(acc[m][n][r]);
      }
    }
  } else {
    // V transposed: [h][t] per batch; regs 0..3 = 4 consecutive t -> 8B store
    const int bb = m0 >> 11;   // tile never crosses batch (2048 % 128 == 0)
    const int tb = m0 & 2047;
#pragma unroll
    for (int m = 0; m < 8; ++m) {
      const int t0 = tb + m * 16 + l4 * 4;
#pragma unroll
      for (int n = 0; n < 8; ++n) {
        const int h = n0 + n * 16 + rl15;
        short4v o;
        o.x = (short)f2bf(acc[m][n][0]);
        o.y = (short)f2bf(acc[m][n][1]);
        o.z = (short)f2bf(acc[m][n][2]);
        o.w = (short)f2bf(acc[m][n][3]);
        *(short4v*)(Vt + ((size_t)bb * Hn + h) * Tn + t0) = o;
      }
    }
  }
}

// ---------------- Scores: single-wave 128x128 blocks, fused row sums ----------------
// E = exp((Q.K)/32) causal-masked; triangular grid 136 tiles x 8 batches = 1088 blocks.
// Row sums of bf16-rounded E reduced across 16 lanes + one atomicAdd per row.
__global__ __launch_bounds__(64, 1) void gemm_scores(const unsigned short* __restrict__ Q,
                                                     const unsigned short* __restrict__ K,
                                                     unsigned short* __restrict__ S,
                                                     float* __restrict__ lrow) {
  const int f = blockIdx.x;
  const int b = f & 7;
  const int u = f >> 3;
  int rt = (int)((sqrtf(8.f * (float)u + 1.f) - 1.f) * 0.5f);
  if ((rt + 1) * (rt + 2) / 2 <= u) ++rt;
  if (rt * (rt + 1) / 2 > u) --rt;
  const int ct = u - rt * (rt + 1) / 2;
  const int i0 = rt * 128, j0 = ct * 128;
  const unsigned short* Ag = Q + (size_t)b * Tn * Hn + (size_t)i0 * Hn;
  const unsigned short* Bg = K + (size_t)b * Tn * Hn + (size_t)j0 * Hn;
  unsigned short* Sb = S + (size_t)b * Tn * Tn;
  __shared__ unsigned short lds[2][2][128 * 32];
  const int lane = threadIdx.x & 63;
  const int rl15 = lane & 15, l4 = lane >> 4;
  const int csw = (l4 ^ (lane & 3) ^ ((lane >> 2) & 3)) & 3;

  f32x4 acc[8][8];
#pragma unroll
  for (int m = 0; m < 8; ++m)
#pragma unroll
    for (int n = 0; n < 8; ++n) acc[m][n] = (f32x4)(0.f);

  KLOOP(Ag, Hn, Bg, Hn, Hn / 32, lds, lane, rl15, csw, acc);

  // epilogue: E store + fused row partial sums
#pragma unroll
  for (int m = 0; m < 8; ++m) {
    const int row = i0 + m * 16 + l4 * 4;
    float rs[4] = {0.f, 0.f, 0.f, 0.f};
#pragma unroll
    for (int n = 0; n < 8; ++n) {
      const int col = j0 + n * 16 + rl15;
#pragma unroll
      for (int r = 0; r < 4; ++r) {
        float e = (col <= row + r) ? __expf(acc[m][n][r] * 0.03125f) : 0.f;
        unsigned short eb = f2bf(e);
        Sb[(size_t)(row + r) * Tn + col] = eb;
        rs[r] += bf2f(eb);
      }
    }
#pragma unroll
    for (int r = 0; r < 4; ++r) {
#pragma unroll
      for (int msk = 1; msk < 16; msk <<= 1)
        rs[r] += __shfl_xor(rs[r], msk);
      if (rl15 == 0)
        atomicAdd(&lrow[(size_t)b * Tn + row + r], rs[r]);
    }
  }
}

// ---------------- Output: single-wave 128x128 blocks ----------------
// O[i][h] = (1/l_i) * sum_k E[i][k]*Vt[h][k]; causal nkt = 4*(rt+1); long-K blocks first.
__global__ __launch_bounds__(64, 1) void gemm_out(const unsigned short* __restrict__ P,
                                                  const unsigned short* __restrict__ Vt,
                                                  const float* __restrict__ lbuf,
                                                  float* __restrict__ O) {
  const int f = blockIdx.x;
  const int b = f & 7;
  const int q = f >> 3;
  const int n0 = (q & 7) * 128;
  const int rt = 15 - (q >> 3);   // long K first
  const int i0 = rt * 128;
  const int nkt = (rt + 1) * 4;   // BK=32 tiles: k < (rt+1)*128
  const unsigned short* Ag = P + (size_t)b * Tn * Tn + (size_t)i0 * Tn;
  const unsigned short* Bg = Vt + (size_t)b * Tn * Hn + (size_t)n0 * Tn;
  __shared__ unsigned short lds[2][2][128 * 32];
  const int lane = threadIdx.x & 63;
  const int rl15 = lane & 15, l4 = lane >> 4;
  const int csw = (l4 ^ (lane & 3) ^ ((lane >> 2) & 3)) & 3;

  f32x4 acc[8][8];
#pragma unroll
  for (int m = 0; m < 8; ++m)
#pragma unroll
    for (int n = 0; n < 8; ++n) acc[m][n] = (f32x4)(0.f);

  KLOOP(Ag, Tn, Bg, Tn, nkt, lds, lane, rl15, csw, acc);

#pragma unroll
  for (int m = 0; m < 8; ++m) {
    const int rb = i0 + m * 16 + l4 * 4;   // % 4 == 0
    float4 lv = *(const float4*)&lbuf[(size_t)b * Tn + rb];
    const float inv0 = 1.f / lv.x, inv1 = 1.f / lv.y, inv2 = 1.f / lv.z, inv3 = 1.f / lv.w;
#pragma unroll
    for (int n = 0; n < 8; ++n) {
      const int col = n0 + n * 16 + rl15;
      O[((size_t)b * Tn + rb + 0) * Hn + col] = acc[m][n][0] * inv0;
      O[((size_t)b * Tn + rb + 1) * Hn + col] = acc[m][n][1] * inv1;
      O[((size_t)b * Tn + rb + 2) * Hn + col] = acc[m][n][2] * inv2;
      O[((size_t)b * Tn + rb + 3) * Hn + col] = acc[m][n][3] * inv3;
    }
  }
}

extern "C" void kernel_launch(void* const* d_in, const int* in_sizes, int n_in,
                              void* d_out, int out_size, void* d_ws, size_t ws_size,
                              hipStream_t stream) {
  const float* x  = (const float*)d_in[0];
  const float* Wq = (const float*)d_in[1];
  const float* Wk = (const float*)d_in[2];
  const float* Wv = (const float*)d_in[3];
  float* out = (float*)d_out;

  // workspace layout (bytes); total 198 MiB
  char* ws = (char*)d_ws;
  const size_t MiB = 1024 * 1024;
  unsigned short* Wt3 = (unsigned short*)(ws + 0 * MiB);    // 3 x 2 MiB, stacked q,k,v
  unsigned short* xb  = (unsigned short*)(ws + 6 * MiB);    // 32 MiB; dead after projections
  unsigned short* Qb  = (unsigned short*)(ws + 38 * MiB);
  unsigned short* Kb  = (unsigned short*)(ws + 70 * MiB);
  unsigned short* Vt  = (unsigned short*)(ws + 102 * MiB);  // V, transposed per-batch [h][t]
  unsigned short* S   = (unsigned short*)(ws + 134 * MiB);  // 64 MiB, holds E = exp(scores)
  float*          lrow = (float*)(ws + 6 * MiB);            // 64 KiB in xb's dead region

  // 1. convert x to bf16
  {
    int n4 = (Mn * Dn) / 4;
    k_convert<<<dim3(n4 / 256), 256, 0, stream>>>(x, xb, n4);
  }
  // 2. convert+transpose all 3 weights (one dispatch)
  {
    dim3 g(Hn / 64, Dn / 64, 3);
    k_cvt_w_t<<<g, 256, 0, stream>>>(Wq, Wk, Wv, Wt3);
  }
  // 3. merged Q/K/V projections, single-wave 128x128 blocks
  {
    gemm_qkv<<<dim3(3072), 64, 0, stream>>>(xb, Wt3, Qb, Kb, Vt);
  }
  // 4. zero denominators (lrow aliases xb; qkv done with xb by here in-stream)
  hipMemsetAsync(lrow, 0, (size_t)Bn * Tn * sizeof(float), stream);
  // 5. scores -> E with fused row sums (triangular grid)
  {
    gemm_scores<<<dim3(1088), 64, 0, stream>>>(Qb, Kb, S, lrow);
  }
  // 6. output with 1/l scaling
  {
    gemm_out<<<dim3(1024), 64, 0, stream>>>(S, Vt, lrow, out);
  }
}